// Round 1
// baseline (1451.382 us; speedup 1.0000x reference)
//
#include <hip/hip_runtime.h>

#define NUM_CLASSES 1000
#define BUF 512
#define DIM 256
#define KTOP 16
#define NQ 65536

// Kernel 1: per-class stable top-16 of 512 areas.
// Rank = #elements strictly greater, plus #equal elements with lower index.
// This reproduces jax.lax.top_k ordering exactly (desc value, lowest index on tie).
__global__ void topk_kernel(const float* __restrict__ areas, int* __restrict__ topidx) {
    __shared__ float s[BUF];
    const int c = blockIdx.x;
    const int t = threadIdx.x;
    s[t] = areas[(size_t)c * BUF + t];
    __syncthreads();
    const float v = s[t];
    int rank = 0;
#pragma unroll 8
    for (int j = 0; j < BUF; ++j) {
        const float w = s[j];
        rank += (w > v) || (w == v && j < t);
    }
    if (rank < KTOP) topidx[c * KTOP + rank] = t;
}

// Kernel 2: gather. One thread per output float4.
// t decomposes as: d4 = t & 63 (16B chunk within row), j = (t>>6)&15 (top-k slot),
// n = t>>10 (query). Each 64-lane wave covers exactly one (n,j) row -> label and
// slot loads are wave-uniform (broadcast), reads/writes coalesced 1 KiB per wave.
__global__ void gather_kernel(const float4* __restrict__ buffer,
                              const int* __restrict__ labels,
                              const int* __restrict__ topidx,
                              float4* __restrict__ out) {
    const unsigned int t = blockIdx.x * blockDim.x + threadIdx.x;
    const unsigned int d4 = t & 63u;
    const unsigned int j  = (t >> 6) & 15u;
    const unsigned int n  = t >> 10;
    const int c    = labels[n];
    const int slot = topidx[c * KTOP + j];
    out[t] = buffer[((size_t)c * BUF + (size_t)slot) * (DIM / 4) + d4];
}

extern "C" void kernel_launch(void* const* d_in, const int* in_sizes, int n_in,
                              void* d_out, int out_size, void* d_ws, size_t ws_size,
                              hipStream_t stream) {
    const float* buffer = (const float*)d_in[0];
    const float* areas  = (const float*)d_in[1];
    // d_in[2] = pointer (unused: reference only uses it for an assert-style check)
    const int* labels   = (const int*)d_in[3];
    // d_in[4] = k scalar (always 16, hard-coded)

    int* topidx = (int*)d_ws;  // NUM_CLASSES * KTOP ints = 64 KB

    topk_kernel<<<NUM_CLASSES, BUF, 0, stream>>>(areas, topidx);

    const unsigned int total4 = (unsigned int)NQ * KTOP * (DIM / 4);  // 67,108,864
    gather_kernel<<<total4 / 256, 256, 0, stream>>>(
        (const float4*)buffer, labels, topidx, (float4*)d_out);
}